// Round 1
// baseline (286.975 us; speedup 1.0000x reference)
//
#include <hip/hip_runtime.h>

typedef unsigned short u16;
typedef __bf16 bf16x8_v __attribute__((ext_vector_type(8)));
typedef float f32x4 __attribute__((ext_vector_type(4)));

// ---------- bf16 helpers (own converters: no header/ABI surprises) ----------
__device__ __forceinline__ u16 f2bf(float f) {
    unsigned u = __float_as_uint(f);
    unsigned r = u + 0x7fffu + ((u >> 16) & 1u);   // RNE; inputs finite
    return (u16)(r >> 16);
}
__device__ __forceinline__ float bf2f(u16 h) {
    return __uint_as_float(((unsigned)h) << 16);
}

// ---------------- conversion kernels ----------------
__global__ __launch_bounds__(256) void k_cvt_x(const float* __restrict__ x,
                                               u16* __restrict__ y, int n) {
    int i = (blockIdx.x * 256 + threadIdx.x) * 4;
    if (i < n) {
        float4 v = *(const float4*)(x + i);
        union { ushort4 u4; u16 h[4]; } o;
        o.h[0] = f2bf(v.x); o.h[1] = f2bf(v.y);
        o.h[2] = f2bf(v.z); o.h[3] = f2bf(v.w);
        *(ushort4*)(y + i) = o.u4;
    }
}

// W [1024,1024] fp32 row-major -> Wt [1024,1024] bf16 with Wt[n][k] = W[k][n]
__global__ __launch_bounds__(256) void k_cvt_wT(const float* __restrict__ W,
                                                u16* __restrict__ Wt) {
    __shared__ float tile[32][33];
    int bx = blockIdx.x;            // n-tile
    int by = blockIdx.y;            // k-tile
    int tx = threadIdx.x & 31;
    int ty = threadIdx.x >> 5;      // 0..7
#pragma unroll
    for (int r = 0; r < 4; ++r)
        tile[ty + r * 8][tx] = W[(by * 32 + ty + r * 8) * 1024 + bx * 32 + tx];
    __syncthreads();
#pragma unroll
    for (int r = 0; r < 4; ++r)
        Wt[(bx * 32 + ty + r * 8) * 1024 + by * 32 + tx] =
            f2bf(tile[tx][ty + r * 8]);
}

// ---------------- GEMM core: NT form ----------------
// C[m][n] = sum_k A[m][k] * Bnt[n][k]; A,Bnt bf16 row-major.
// Block 256 thr = 4 waves (2x2), tile 128x128, BK=32, acc 4x4 per wave.
__device__ __forceinline__ void gemm_core_nt(const u16* __restrict__ A,   // + m0*lda
                                             const u16* __restrict__ B,   // + n0*ldb
                                             int lda, int ldb, int kLen,
                                             f32x4 acc[4][4]) {
    __shared__ u16 As[128 * 32];
    __shared__ u16 Bs[128 * 32];
    const int tid = threadIdx.x;
    const int c0 = tid, c1 = tid + 256;               // 16B chunks, 512 per tile
    const int r0 = c0 >> 2, o0 = (c0 & 3) * 8;
    const int r1 = c1 >> 2, o1 = (c1 & 3) * 8;

    const int wave = tid >> 6;
    const int lane = tid & 63;
    const int wm = (wave >> 1) * 64;
    const int wn = (wave & 1) * 64;
    const int row16 = lane & 15;
    const int quad = lane >> 4;

#pragma unroll
    for (int i = 0; i < 4; ++i)
#pragma unroll
        for (int j = 0; j < 4; ++j) {
            f32x4 z = {0.f, 0.f, 0.f, 0.f};
            acc[i][j] = z;
        }

    int4 pa0 = *(const int4*)(A + r0 * lda + o0);
    int4 pa1 = *(const int4*)(A + r1 * lda + o1);
    int4 pb0 = *(const int4*)(B + r0 * ldb + o0);
    int4 pb1 = *(const int4*)(B + r1 * ldb + o1);

    const int ktiles = kLen >> 5;
    for (int kt = 0; kt < ktiles; ++kt) {
        __syncthreads();
        *(int4*)(As + c0 * 8) = pa0;
        *(int4*)(As + c1 * 8) = pa1;
        *(int4*)(Bs + c0 * 8) = pb0;
        *(int4*)(Bs + c1 * 8) = pb1;
        __syncthreads();
        if (kt + 1 < ktiles) {
            const u16* A2 = A + (kt + 1) * 32;
            const u16* B2 = B + (kt + 1) * 32;
            pa0 = *(const int4*)(A2 + r0 * lda + o0);
            pa1 = *(const int4*)(A2 + r1 * lda + o1);
            pb0 = *(const int4*)(B2 + r0 * ldb + o0);
            pb1 = *(const int4*)(B2 + r1 * ldb + o1);
        }
        bf16x8_v af[4], bfv[4];
#pragma unroll
        for (int i = 0; i < 4; ++i)
            af[i] = *(const bf16x8_v*)(As + (wm + i * 16 + row16) * 32 + quad * 8);
#pragma unroll
        for (int j = 0; j < 4; ++j)
            bfv[j] = *(const bf16x8_v*)(Bs + (wn + j * 16 + row16) * 32 + quad * 8);
#pragma unroll
        for (int i = 0; i < 4; ++i)
#pragma unroll
            for (int j = 0; j < 4; ++j)
                acc[i][j] = __builtin_amdgcn_mfma_f32_16x16x32_bf16(
                    af[i], bfv[j], acc[i][j], 0, 0, 0);
    }
}

// ---------------- GEMM kernels ----------------
// Q/K projection: Y[m][n], m over 8192, n over 1024. grid (8, 64)
__global__ __launch_bounds__(256) void k_gemm_qk(const u16* __restrict__ X,
                                                 const u16* __restrict__ Wt,
                                                 u16* __restrict__ Y) {
    const int n0 = blockIdx.x * 128, m0 = blockIdx.y * 128;
    f32x4 acc[4][4];
    gemm_core_nt(X + (size_t)m0 * 1024, Wt + (size_t)n0 * 1024, 1024, 1024, 1024, acc);
    const int tid = threadIdx.x, wave = tid >> 6, lane = tid & 63;
    const int wm = (wave >> 1) * 64, wn = (wave & 1) * 64;
    const int row16 = lane & 15, quad = lane >> 4;
#pragma unroll
    for (int i = 0; i < 4; ++i)
#pragma unroll
        for (int j = 0; j < 4; ++j) {
            int m = m0 + wm + i * 16 + quad * 4;
            int n = n0 + wn + j * 16 + row16;
#pragma unroll
            for (int r = 0; r < 4; ++r)
                Y[(size_t)(m + r) * 1024 + n] = f2bf(acc[i][j][r]);
        }
}

// V projection with transposed write: Vt[b][e][s] (e over 1024, s over 2048)
__global__ __launch_bounds__(256) void k_gemm_vt(const u16* __restrict__ X,
                                                 const u16* __restrict__ Wt,
                                                 u16* __restrict__ Vt) {
    const int n0 = blockIdx.x * 128, m0 = blockIdx.y * 128;
    f32x4 acc[4][4];
    gemm_core_nt(X + (size_t)m0 * 1024, Wt + (size_t)n0 * 1024, 1024, 1024, 1024, acc);
    const int tid = threadIdx.x, wave = tid >> 6, lane = tid & 63;
    const int wm = (wave >> 1) * 64, wn = (wave & 1) * 64;
    const int row16 = lane & 15, quad = lane >> 4;
#pragma unroll
    for (int i = 0; i < 4; ++i)
#pragma unroll
        for (int j = 0; j < 4; ++j) {
            int m = m0 + wm + i * 16 + quad * 4;   // global row in [0,8192)
            int n = n0 + wn + j * 16 + row16;      // feature e
            int b = m >> 11, s = m & 2047;
            union { ushort4 u4; u16 h[4]; } o;
#pragma unroll
            for (int r = 0; r < 4; ++r) o.h[r] = f2bf(acc[i][j][r]);
            *(ushort4*)(Vt + ((size_t)b * 1024 + n) * 2048 + s) = o.u4;
        }
}

// Scores: S[b][i][j] = Q[b,i,:]·K[b,j,:] / 32, lower-triangular tiles only.
// grid (136, B)
__global__ __launch_bounds__(256) void k_gemm_scores(const u16* __restrict__ Q,
                                                     const u16* __restrict__ Kb,
                                                     u16* __restrict__ Sb) {
    int t = blockIdx.x, b = blockIdx.y;
    int mt = 0;
    while ((mt + 1) * (mt + 2) / 2 <= t) ++mt;
    int nt = t - mt * (mt + 1) / 2;
    const u16* Qp = Q + (size_t)b * 2048 * 1024 + (size_t)mt * 128 * 1024;
    const u16* Kp = Kb + (size_t)b * 2048 * 1024 + (size_t)nt * 128 * 1024;
    u16* Sp = Sb + (size_t)b * 2048 * 2048;
    f32x4 acc[4][4];
    gemm_core_nt(Qp, Kp, 1024, 1024, 1024, acc);
    const int tid = threadIdx.x, wave = tid >> 6, lane = tid & 63;
    const int wm = (wave >> 1) * 64, wn = (wave & 1) * 64;
    const int row16 = lane & 15, quad = lane >> 4;
#pragma unroll
    for (int i = 0; i < 4; ++i)
#pragma unroll
        for (int j = 0; j < 4; ++j) {
            int m = mt * 128 + wm + i * 16 + quad * 4;
            int n = nt * 128 + wn + j * 16 + row16;
#pragma unroll
            for (int r = 0; r < 4; ++r)
                Sp[(size_t)(m + r) * 2048 + n] = f2bf(acc[i][j][r] * 0.03125f);
        }
}

// PV: O[b][i][e] = sum_j P[b][i][j] * V[b][j][e], k-extent (mt+1)*128.
// grid (8, 16, B)
__global__ __launch_bounds__(256) void k_gemm_pv(const u16* __restrict__ P,
                                                 const u16* __restrict__ Vt,
                                                 float* __restrict__ O) {
    const int nt = blockIdx.x, mt = blockIdx.y, b = blockIdx.z;
    const u16* Pp = P + (size_t)b * 2048 * 2048 + (size_t)mt * 128 * 2048;
    const u16* Vp = Vt + (size_t)b * 1024 * 2048 + (size_t)nt * 128 * 2048;
    f32x4 acc[4][4];
    gemm_core_nt(Pp, Vp, 2048, 2048, (mt + 1) * 128, acc);
    float* Op = O + (size_t)b * 2048 * 1024;
    const int tid = threadIdx.x, wave = tid >> 6, lane = tid & 63;
    const int wm = (wave >> 1) * 64, wn = (wave & 1) * 64;
    const int row16 = lane & 15, quad = lane >> 4;
#pragma unroll
    for (int i = 0; i < 4; ++i)
#pragma unroll
        for (int j = 0; j < 4; ++j) {
            int m = mt * 128 + wm + i * 16 + quad * 4;
            int n = nt * 128 + wn + j * 16 + row16;
#pragma unroll
            for (int r = 0; r < 4; ++r)
                Op[(size_t)(m + r) * 1024 + n] = acc[i][j][r];
        }
}

// ---------------- softmax (in-place, fp32 math on bf16 scores) ----------------
// grid (2048, B). Row i: valid length L=i+1, zero out [L, Lpad) where
// Lpad = ((i>>7)+1)*128 (== PV's k-extent for this row's tile).
__global__ __launch_bounds__(256) void k_softmax(u16* __restrict__ Sb) {
    const int i = blockIdx.x, b = blockIdx.y;
    u16* row = Sb + ((size_t)b * 2048 + i) * 2048;
    const int L = i + 1;
    const int Lpad = ((i >> 7) + 1) << 7;
    const int tid = threadIdx.x;

    float v[8];
    float mx = -3.0e38f;
#pragma unroll
    for (int u = 0; u < 8; ++u) {
        int j = tid + u * 256;
        float val = -3.0e38f;
        if (j < L) val = bf2f(row[j]);
        v[u] = val;
        mx = fmaxf(mx, val);
    }
    for (int off = 32; off > 0; off >>= 1) mx = fmaxf(mx, __shfl_xor(mx, off));
    __shared__ float redm[4];
    if ((tid & 63) == 0) redm[tid >> 6] = mx;
    __syncthreads();
    mx = fmaxf(fmaxf(redm[0], redm[1]), fmaxf(redm[2], redm[3]));

    float e[8];
    float sum = 0.f;
#pragma unroll
    for (int u = 0; u < 8; ++u) {
        int j = tid + u * 256;
        float t = 0.f;
        if (j < L) t = __expf(v[u] - mx);
        e[u] = t;
        sum += t;
    }
    for (int off = 32; off > 0; off >>= 1) sum += __shfl_xor(sum, off);
    __shared__ float reds[4];
    if ((tid & 63) == 0) reds[tid >> 6] = sum;
    __syncthreads();
    sum = reds[0] + reds[1] + reds[2] + reds[3];
    float inv = 1.0f / sum;

#pragma unroll
    for (int u = 0; u < 8; ++u) {
        int j = tid + u * 256;
        if (j < L) row[j] = f2bf(e[u] * inv);
        else if (j < Lpad) row[j] = 0;
    }
}

// ---------------- launcher ----------------
extern "C" void kernel_launch(void* const* d_in, const int* in_sizes, int n_in,
                              void* d_out, int out_size, void* d_ws, size_t ws_size,
                              hipStream_t stream) {
    const float* x  = (const float*)d_in[0];
    const float* Wq = (const float*)d_in[1];
    const float* Wk = (const float*)d_in[2];
    const float* Wv = (const float*)d_in[3];
    float* out = (float*)d_out;
    char* ws = (char*)d_ws;

    // workspace layout (102 MB total)
    u16* xb  = (u16*)(ws);                          // 16 MB: x bf16 [8192,1024]
    u16* Wtq = (u16*)(ws + (16u << 20));            //  2 MB: Wq^T bf16
    u16* Wtk = (u16*)(ws + (18u << 20));            //  2 MB
    u16* Wtv = (u16*)(ws + (20u << 20));            //  2 MB
    u16* Qb  = (u16*)(ws + (22u << 20));            // 16 MB: Q bf16 [8192,1024]
    u16* Kb  = (u16*)(ws + (38u << 20));            // 16 MB: K bf16
    u16* Vt  = (u16*)(ws + (54u << 20));            // 16 MB: V^T bf16 [B,1024,2048]
    u16* Sb  = (u16*)(ws + (70u << 20));            // 32 MB: scores/P bf16 [B,2048,2048]

    k_cvt_x<<<8192, 256, 0, stream>>>(x, xb, 8192 * 1024);
    k_cvt_wT<<<dim3(32, 32), 256, 0, stream>>>(Wq, Wtq);
    k_cvt_wT<<<dim3(32, 32), 256, 0, stream>>>(Wk, Wtk);
    k_cvt_wT<<<dim3(32, 32), 256, 0, stream>>>(Wv, Wtv);

    k_gemm_qk<<<dim3(8, 64), 256, 0, stream>>>(xb, Wtq, Qb);
    k_gemm_qk<<<dim3(8, 64), 256, 0, stream>>>(xb, Wtk, Kb);
    k_gemm_vt<<<dim3(8, 64), 256, 0, stream>>>(xb, Wtv, Vt);

    k_gemm_scores<<<dim3(136, 4), 256, 0, stream>>>(Qb, Kb, Sb);
    k_softmax<<<dim3(2048, 4), 256, 0, stream>>>(Sb);
    k_gemm_pv<<<dim3(8, 16, 4), 256, 0, stream>>>(Sb, Vt, out);
}

// Round 2
// 279.215 us; speedup vs baseline: 1.0278x; 1.0278x over previous
//
#include <hip/hip_runtime.h>

typedef unsigned short u16;
typedef __bf16 bf16x8_v __attribute__((ext_vector_type(8)));
typedef float f32x4 __attribute__((ext_vector_type(4)));

// ---------- bf16 helpers ----------
__device__ __forceinline__ u16 f2bf(float f) {
    unsigned u = __float_as_uint(f);
    unsigned r = u + 0x7fffu + ((u >> 16) & 1u);   // RNE; inputs finite
    return (u16)(r >> 16);
}
__device__ __forceinline__ float bf2f(u16 h) {
    return __uint_as_float(((unsigned)h) << 16);
}

// async global->LDS, 16B per lane; lds dst = wave-uniform base + lane*16
__device__ __forceinline__ void gll16(const u16* g, u16* l) {
    __builtin_amdgcn_global_load_lds(
        (const __attribute__((address_space(1))) void*)g,
        (__attribute__((address_space(3))) void*)l, 16, 0, 0);
}

// ---------------- conversion kernels ----------------
__global__ __launch_bounds__(256) void k_cvt_x(const float* __restrict__ x,
                                               u16* __restrict__ y, int n) {
    int i = (blockIdx.x * 256 + threadIdx.x) * 4;
    if (i < n) {
        float4 v = *(const float4*)(x + i);
        union { ushort4 u4; u16 h[4]; } o;
        o.h[0] = f2bf(v.x); o.h[1] = f2bf(v.y);
        o.h[2] = f2bf(v.z); o.h[3] = f2bf(v.w);
        *(ushort4*)(y + i) = o.u4;
    }
}

// W [1024,1024] fp32 row-major -> Wt [1024,1024] bf16 with Wt[n][k] = W[k][n]
__global__ __launch_bounds__(256) void k_cvt_wT(const float* __restrict__ W,
                                                u16* __restrict__ Wt) {
    __shared__ float tile[32][33];
    int bx = blockIdx.x;            // n-tile
    int by = blockIdx.y;            // k-tile
    int tx = threadIdx.x & 31;
    int ty = threadIdx.x >> 5;      // 0..7
#pragma unroll
    for (int r = 0; r < 4; ++r)
        tile[ty + r * 8][tx] = W[(by * 32 + ty + r * 8) * 1024 + bx * 32 + tx];
    __syncthreads();
#pragma unroll
    for (int r = 0; r < 4; ++r)
        Wt[(bx * 32 + ty + r * 8) * 1024 + by * 32 + tx] =
            f2bf(tile[tx][ty + r * 8]);
}

// ---------------- GEMM core: NT form, global_load_lds staging ----------------
// C[m][n] = sum_k A[m][k] * Bnt[n][k]; A,Bnt bf16 row-major.
// Block 256 thr = 4 waves (2x2), tile 128x128, BK=32, acc 4x4 per wave.
__device__ __forceinline__ void gemm_core_nt(const u16* __restrict__ A,   // + m0*lda
                                             const u16* __restrict__ B,   // + n0*ldb
                                             int lda, int ldb, int kLen,
                                             f32x4 acc[4][4]) {
    __shared__ u16 As[128 * 32];
    __shared__ u16 Bs[128 * 32];
    const int tid = threadIdx.x;
    const int wave = tid >> 6;
    const int lane = tid & 63;
    // staging: chunk c=tid covers LDS bytes [c*16, c*16+16) == row (c>>2), col (c&3)*8
    const int r0 = tid >> 2, o0 = (tid & 3) * 8;
    const int r1 = r0 + 64;                 // chunk tid+256
    u16* AsW0 = As + wave * 512;            // lane*16B appended by HW
    u16* AsW1 = As + 2048 + wave * 512;
    u16* BsW0 = Bs + wave * 512;
    u16* BsW1 = Bs + 2048 + wave * 512;

    const int wm = (wave >> 1) * 64;
    const int wn = (wave & 1) * 64;
    const int row16 = lane & 15;
    const int quad = lane >> 4;

#pragma unroll
    for (int i = 0; i < 4; ++i)
#pragma unroll
        for (int j = 0; j < 4; ++j) {
            f32x4 z = {0.f, 0.f, 0.f, 0.f};
            acc[i][j] = z;
        }

    const u16* Ag0 = A + r0 * lda + o0;
    const u16* Ag1 = A + r1 * lda + o0;
    const u16* Bg0 = B + r0 * ldb + o0;
    const u16* Bg1 = B + r1 * ldb + o0;

    const int ktiles = kLen >> 5;
    for (int kt = 0; kt < ktiles; ++kt) {
        __syncthreads();                    // all waves done reading prev tile
        gll16(Ag0 + kt * 32, AsW0);
        gll16(Ag1 + kt * 32, AsW1);
        gll16(Bg0 + kt * 32, BsW0);
        gll16(Bg1 + kt * 32, BsW1);
        __syncthreads();                    // compiler drains vmcnt before barrier
        bf16x8_v af[4], bfv[4];
#pragma unroll
        for (int i = 0; i < 4; ++i)
            af[i] = *(const bf16x8_v*)(As + (wm + i * 16 + row16) * 32 + quad * 8);
#pragma unroll
        for (int j = 0; j < 4; ++j)
            bfv[j] = *(const bf16x8_v*)(Bs + (wn + j * 16 + row16) * 32 + quad * 8);
#pragma unroll
        for (int i = 0; i < 4; ++i)
#pragma unroll
            for (int j = 0; j < 4; ++j)
                acc[i][j] = __builtin_amdgcn_mfma_f32_16x16x32_bf16(
                    af[i], bfv[j], acc[i][j], 0, 0, 0);
    }
}

// ---------------- fused QKV projection ----------------
// Wt3 = [Wq^T ; Wk^T ; Wv^T] bf16 [3072,1024]. grid (24, 64).
// n0g<1024 -> Q, <2048 -> K, else V written transposed Vt[b][e][s].
__global__ __launch_bounds__(256) void k_gemm_proj(const u16* __restrict__ X,
                                                   const u16* __restrict__ Wt3,
                                                   u16* __restrict__ Qb,
                                                   u16* __restrict__ Kb,
                                                   u16* __restrict__ Vt) {
    const int n0g = blockIdx.x * 128, m0 = blockIdx.y * 128;
    f32x4 acc[4][4];
    gemm_core_nt(X + (size_t)m0 * 1024, Wt3 + (size_t)n0g * 1024, 1024, 1024, 1024, acc);
    const int tid = threadIdx.x, wave = tid >> 6, lane = tid & 63;
    const int wm = (wave >> 1) * 64, wn = (wave & 1) * 64;
    const int row16 = lane & 15, quad = lane >> 4;
    if (n0g < 2048) {
        u16* Y = (n0g < 1024) ? Qb : Kb;
        const int n0 = n0g & 1023;
#pragma unroll
        for (int i = 0; i < 4; ++i)
#pragma unroll
            for (int j = 0; j < 4; ++j) {
                int m = m0 + wm + i * 16 + quad * 4;
                int n = n0 + wn + j * 16 + row16;
#pragma unroll
                for (int r = 0; r < 4; ++r)
                    Y[(size_t)(m + r) * 1024 + n] = f2bf(acc[i][j][r]);
            }
    } else {
        const int n0 = n0g - 2048;
#pragma unroll
        for (int i = 0; i < 4; ++i)
#pragma unroll
            for (int j = 0; j < 4; ++j) {
                int m = m0 + wm + i * 16 + quad * 4;   // row in [0,8192)
                int n = n0 + wn + j * 16 + row16;      // feature e
                int b = m >> 11, s = m & 2047;
                union { ushort4 u4; u16 h[4]; } o;
#pragma unroll
                for (int r = 0; r < 4; ++r) o.h[r] = f2bf(acc[i][j][r]);
                *(ushort4*)(Vt + ((size_t)b * 1024 + n) * 2048 + s) = o.u4;
            }
    }
}

// Scores: S[b][i][j] = Q[b,i,:]·K[b,j,:] / 32, lower-triangular tiles only.
// grid (136, B)
__global__ __launch_bounds__(256) void k_gemm_scores(const u16* __restrict__ Q,
                                                     const u16* __restrict__ Kb,
                                                     u16* __restrict__ Sb) {
    int t = blockIdx.x, b = blockIdx.y;
    int mt = 0;
    while ((mt + 1) * (mt + 2) / 2 <= t) ++mt;
    int nt = t - mt * (mt + 1) / 2;
    const u16* Qp = Q + (size_t)b * 2048 * 1024 + (size_t)mt * 128 * 1024;
    const u16* Kp = Kb + (size_t)b * 2048 * 1024 + (size_t)nt * 128 * 1024;
    u16* Sp = Sb + (size_t)b * 2048 * 2048;
    f32x4 acc[4][4];
    gemm_core_nt(Qp, Kp, 1024, 1024, 1024, acc);
    const int tid = threadIdx.x, wave = tid >> 6, lane = tid & 63;
    const int wm = (wave >> 1) * 64, wn = (wave & 1) * 64;
    const int row16 = lane & 15, quad = lane >> 4;
#pragma unroll
    for (int i = 0; i < 4; ++i)
#pragma unroll
        for (int j = 0; j < 4; ++j) {
            int m = mt * 128 + wm + i * 16 + quad * 4;
            int n = nt * 128 + wn + j * 16 + row16;
#pragma unroll
            for (int r = 0; r < 4; ++r)
                Sp[(size_t)(m + r) * 2048 + n] = f2bf(acc[i][j][r] * 0.03125f);
        }
}

// PV: O[b][i][e] = sum_j P[b][i][j] * V[b][j][e], k-extent (mt+1)*128.
// grid (8, 16, B)
__global__ __launch_bounds__(256) void k_gemm_pv(const u16* __restrict__ P,
                                                 const u16* __restrict__ Vt,
                                                 float* __restrict__ O) {
    const int nt = blockIdx.x, mt = blockIdx.y, b = blockIdx.z;
    const u16* Pp = P + (size_t)b * 2048 * 2048 + (size_t)mt * 128 * 2048;
    const u16* Vp = Vt + (size_t)b * 1024 * 2048 + (size_t)nt * 128 * 2048;
    f32x4 acc[4][4];
    gemm_core_nt(Pp, Vp, 2048, 2048, (mt + 1) * 128, acc);
    float* Op = O + (size_t)b * 2048 * 1024;
    const int tid = threadIdx.x, wave = tid >> 6, lane = tid & 63;
    const int wm = (wave >> 1) * 64, wn = (wave & 1) * 64;
    const int row16 = lane & 15, quad = lane >> 4;
#pragma unroll
    for (int i = 0; i < 4; ++i)
#pragma unroll
        for (int j = 0; j < 4; ++j) {
            int m = mt * 128 + wm + i * 16 + quad * 4;
            int n = nt * 128 + wn + j * 16 + row16;
#pragma unroll
            for (int r = 0; r < 4; ++r)
                Op[(size_t)(m + r) * 1024 + n] = acc[i][j][r];
        }
}

// ---------------- softmax (in-place, fp32 math on bf16 scores) ----------------
// grid (2048, B). Row i: valid length L=i+1, zero out [L, Lpad) where
// Lpad = ((i>>7)+1)*128 (== PV's k-extent for this row's tile).
__global__ __launch_bounds__(256) void k_softmax(u16* __restrict__ Sb) {
    const int i = blockIdx.x, b = blockIdx.y;
    u16* row = Sb + ((size_t)b * 2048 + i) * 2048;
    const int L = i + 1;
    const int Lpad = ((i >> 7) + 1) << 7;
    const int tid = threadIdx.x;

    float v[8];
    float mx = -3.0e38f;
#pragma unroll
    for (int u = 0; u < 8; ++u) {
        int j = tid + u * 256;
        float val = -3.0e38f;
        if (j < L) val = bf2f(row[j]);
        v[u] = val;
        mx = fmaxf(mx, val);
    }
    for (int off = 32; off > 0; off >>= 1) mx = fmaxf(mx, __shfl_xor(mx, off));
    __shared__ float redm[4];
    if ((tid & 63) == 0) redm[tid >> 6] = mx;
    __syncthreads();
    mx = fmaxf(fmaxf(redm[0], redm[1]), fmaxf(redm[2], redm[3]));

    float e[8];
    float sum = 0.f;
#pragma unroll
    for (int u = 0; u < 8; ++u) {
        int j = tid + u * 256;
        float t = 0.f;
        if (j < L) t = __expf(v[u] - mx);
        e[u] = t;
        sum += t;
    }
    for (int off = 32; off > 0; off >>= 1) sum += __shfl_xor(sum, off);
    __shared__ float reds[4];
    if ((tid & 63) == 0) reds[tid >> 6] = sum;
    __syncthreads();
    sum = reds[0] + reds[1] + reds[2] + reds[3];
    float inv = 1.0f / sum;

#pragma unroll
    for (int u = 0; u < 8; ++u) {
        int j = tid + u * 256;
        if (j < L) row[j] = f2bf(e[u] * inv);
        else if (j < Lpad) row[j] = 0;
    }
}

// ---------------- launcher ----------------
extern "C" void kernel_launch(void* const* d_in, const int* in_sizes, int n_in,
                              void* d_out, int out_size, void* d_ws, size_t ws_size,
                              hipStream_t stream) {
    const float* x  = (const float*)d_in[0];
    const float* Wq = (const float*)d_in[1];
    const float* Wk = (const float*)d_in[2];
    const float* Wv = (const float*)d_in[3];
    float* out = (float*)d_out;
    char* ws = (char*)d_ws;

    // workspace layout (102 MB total)
    u16* xb  = (u16*)(ws);                          // 16 MB: x bf16 [8192,1024]
    u16* Wt3 = (u16*)(ws + (16u << 20));            //  6 MB: [Wq^T;Wk^T;Wv^T] bf16 [3072,1024]
    u16* Qb  = (u16*)(ws + (22u << 20));            // 16 MB: Q bf16 [8192,1024]
    u16* Kb  = (u16*)(ws + (38u << 20));            // 16 MB: K bf16
    u16* Vt  = (u16*)(ws + (54u << 20));            // 16 MB: V^T bf16 [B,1024,2048]
    u16* Sb  = (u16*)(ws + (70u << 20));            // 32 MB: scores/P bf16 [B,2048,2048]

    k_cvt_x<<<8192, 256, 0, stream>>>(x, xb, 8192 * 1024);
    k_cvt_wT<<<dim3(32, 32), 256, 0, stream>>>(Wq, Wt3);
    k_cvt_wT<<<dim3(32, 32), 256, 0, stream>>>(Wk, Wt3 + 1024 * 1024);
    k_cvt_wT<<<dim3(32, 32), 256, 0, stream>>>(Wv, Wt3 + 2 * 1024 * 1024);

    k_gemm_proj<<<dim3(24, 64), 256, 0, stream>>>(xb, Wt3, Qb, Kb, Vt);

    k_gemm_scores<<<dim3(136, 4), 256, 0, stream>>>(Qb, Kb, Sb);
    k_softmax<<<dim3(2048, 4), 256, 0, stream>>>(Sb);
    k_gemm_pv<<<dim3(8, 16, 4), 256, 0, stream>>>(Sb, Vt, out);
}

// Round 3
// 271.262 us; speedup vs baseline: 1.0579x; 1.0293x over previous
//
#include <hip/hip_runtime.h>

typedef unsigned short u16;
typedef __bf16 bf16x8_v __attribute__((ext_vector_type(8)));
typedef float f32x4 __attribute__((ext_vector_type(4)));

// ---------- bf16 helpers ----------
__device__ __forceinline__ u16 f2bf(float f) {
    unsigned u = __float_as_uint(f);
    unsigned r = u + 0x7fffu + ((u >> 16) & 1u);   // RNE; inputs finite
    return (u16)(r >> 16);
}
__device__ __forceinline__ float bf2f(u16 h) {
    return __uint_as_float(((unsigned)h) << 16);
}

// async global->LDS, 16B per lane; lds dst = wave-uniform base + lane*16
__device__ __forceinline__ void gll16(const u16* g, u16* l) {
    __builtin_amdgcn_global_load_lds(
        (const __attribute__((address_space(1))) void*)g,
        (__attribute__((address_space(3))) void*)l, 16, 0, 0);
}

// ---------------- conversion kernels ----------------
__global__ __launch_bounds__(256) void k_cvt_x(const float* __restrict__ x,
                                               u16* __restrict__ y, int n) {
    int i = (blockIdx.x * 256 + threadIdx.x) * 8;
    if (i < n) {
        float4 a = *(const float4*)(x + i);
        float4 b = *(const float4*)(x + i + 4);
        union { int4 p; u16 h[8]; } o;
        o.h[0] = f2bf(a.x); o.h[1] = f2bf(a.y); o.h[2] = f2bf(a.z); o.h[3] = f2bf(a.w);
        o.h[4] = f2bf(b.x); o.h[5] = f2bf(b.y); o.h[6] = f2bf(b.z); o.h[7] = f2bf(b.w);
        *(int4*)(y + i) = o.p;
    }
}

// W [1024,1024] fp32 row-major -> Wt3 slice bf16 with Wt[n][k] = W[k][n].
// grid (32, 32, 3): z selects Wq/Wk/Wv.
__global__ __launch_bounds__(256) void k_cvt_w3(const float* __restrict__ Wq,
                                                const float* __restrict__ Wk,
                                                const float* __restrict__ Wv,
                                                u16* __restrict__ Wt3) {
    __shared__ float tile[32][33];
    const int z = blockIdx.z;
    const float* W = (z == 0) ? Wq : (z == 1) ? Wk : Wv;
    u16* Wt = Wt3 + (size_t)z * 1024 * 1024;
    int bx = blockIdx.x;            // n-tile
    int by = blockIdx.y;            // k-tile
    int tx = threadIdx.x & 31;
    int ty = threadIdx.x >> 5;      // 0..7
#pragma unroll
    for (int r = 0; r < 4; ++r)
        tile[ty + r * 8][tx] = W[(by * 32 + ty + r * 8) * 1024 + bx * 32 + tx];
    __syncthreads();
#pragma unroll
    for (int r = 0; r < 4; ++r)
        Wt[(bx * 32 + ty + r * 8) * 1024 + by * 32 + tx] =
            f2bf(tile[tx][ty + r * 8]);
}

// ---------------- GEMM core: NT form, global_load_lds staging ----------------
// C[m][n] = sum_k A[m][k] * Bnt[n][k]; A,Bnt bf16 row-major.
// Block 256 thr = 4 waves (2x2), tile 128x128, BK=32, acc 4x4 per wave.
// smem: 16 KB (As 8 KB | Bs 8 KB), reused by the epilogue afterwards.
__device__ __forceinline__ void gemm_core_nt(const u16* __restrict__ A,   // + m0*lda
                                             const u16* __restrict__ B,   // + n0*ldb
                                             int lda, int ldb, int kLen,
                                             u16* smem, f32x4 acc[4][4]) {
    u16* As = smem;
    u16* Bs = smem + 128 * 32;
    const int tid = threadIdx.x;
    const int wave = tid >> 6;
    const int lane = tid & 63;
    // staging: chunk c=tid covers LDS bytes [c*16, c*16+16) == row (c>>2), col (c&3)*8
    const int r0 = tid >> 2, o0 = (tid & 3) * 8;
    const int r1 = r0 + 64;                 // chunk tid+256
    u16* AsW0 = As + wave * 512;            // lane*16B appended by HW
    u16* AsW1 = As + 2048 + wave * 512;
    u16* BsW0 = Bs + wave * 512;
    u16* BsW1 = Bs + 2048 + wave * 512;

    const int wm = (wave >> 1) * 64;
    const int wn = (wave & 1) * 64;
    const int row16 = lane & 15;
    const int quad = lane >> 4;

#pragma unroll
    for (int i = 0; i < 4; ++i)
#pragma unroll
        for (int j = 0; j < 4; ++j) {
            f32x4 z = {0.f, 0.f, 0.f, 0.f};
            acc[i][j] = z;
        }

    const u16* Ag0 = A + r0 * lda + o0;
    const u16* Ag1 = A + r1 * lda + o0;
    const u16* Bg0 = B + r0 * ldb + o0;
    const u16* Bg1 = B + r1 * ldb + o0;

    const int ktiles = kLen >> 5;
    for (int kt = 0; kt < ktiles; ++kt) {
        __syncthreads();                    // all waves done reading prev tile
        gll16(Ag0 + kt * 32, AsW0);
        gll16(Ag1 + kt * 32, AsW1);
        gll16(Bg0 + kt * 32, BsW0);
        gll16(Bg1 + kt * 32, BsW1);
        __syncthreads();                    // vmcnt drained before barrier
        bf16x8_v af[4], bfv[4];
#pragma unroll
        for (int i = 0; i < 4; ++i)
            af[i] = *(const bf16x8_v*)(As + (wm + i * 16 + row16) * 32 + quad * 8);
#pragma unroll
        for (int j = 0; j < 4; ++j)
            bfv[j] = *(const bf16x8_v*)(Bs + (wn + j * 16 + row16) * 32 + quad * 8);
#pragma unroll
        for (int i = 0; i < 4; ++i)
#pragma unroll
            for (int j = 0; j < 4; ++j)
                acc[i][j] = __builtin_amdgcn_mfma_f32_16x16x32_bf16(
                    af[i], bfv[j], acc[i][j], 0, 0, 0);
    }
}

// Coalesced bf16 epilogue: transpose this wave's 64x64 tile through its 4 KB
// LDS slice, store as dwordx4 (64B row segments). Caller must __syncthreads()
// after the main loop before calling (smem is being repurposed).
// g = output origin of this wave's tile: base + (m0+wm)*ldg + (n0+wn).
__device__ __forceinline__ void epi_bf16(const f32x4 acc[4][4], u16* smem,
                                         u16* __restrict__ g, int ldg, float scale) {
    const int tid = threadIdx.x;
    const int wave = tid >> 6, lane = tid & 63;
    const int row16 = lane & 15, quad = lane >> 4;
    u16* Ts = smem + wave * 2048;           // 64 rows x 32 cols (u16)
#pragma unroll
    for (int jh = 0; jh < 2; ++jh) {        // two 64x32 halves (cols jh*32..)
#pragma unroll
        for (int i = 0; i < 4; ++i)
#pragma unroll
            for (int jj = 0; jj < 2; ++jj) {
                const int j = jh * 2 + jj;
#pragma unroll
                for (int r = 0; r < 4; ++r)
                    Ts[(i * 16 + quad * 4 + r) * 32 + jj * 16 + row16] =
                        f2bf(acc[i][j][r] * scale);
            }
        // per-wave DS ordering guarantees write->read visibility (same wave)
#pragma unroll
        for (int s = 0; s < 4; ++s) {
            const int row = s * 16 + (lane >> 2);
            int4 val = *(const int4*)(Ts + row * 32 + (lane & 3) * 8);
            *(int4*)(g + (size_t)row * ldg + jh * 32 + (lane & 3) * 8) = val;
        }
    }
}

// ---------------- fused QKV projection ----------------
// Wt3 = [Wq^T ; Wk^T ; Wv^T] bf16 [3072,1024]. grid (24, 64).
// n0g<1024 -> Q, <2048 -> K, else V written transposed Vt[b][e][s].
__global__ __launch_bounds__(256) void k_gemm_proj(const u16* __restrict__ X,
                                                   const u16* __restrict__ Wt3,
                                                   u16* __restrict__ Qb,
                                                   u16* __restrict__ Kb,
                                                   u16* __restrict__ Vt) {
    __shared__ u16 smem[128 * 64];
    const int n0g = blockIdx.x * 128, m0 = blockIdx.y * 128;
    f32x4 acc[4][4];
    gemm_core_nt(X + (size_t)m0 * 1024, Wt3 + (size_t)n0g * 1024, 1024, 1024, 1024,
                 smem, acc);
    const int tid = threadIdx.x, wave = tid >> 6, lane = tid & 63;
    const int wm = (wave >> 1) * 64, wn = (wave & 1) * 64;
    const int row16 = lane & 15, quad = lane >> 4;
    if (n0g < 2048) {
        u16* Y = (n0g < 1024) ? Qb : Kb;
        const int n0 = n0g & 1023;
        __syncthreads();
        epi_bf16(acc, smem, Y + (size_t)(m0 + wm) * 1024 + n0 + wn, 1024, 1.0f);
    } else {
        const int n0 = n0g - 2048;
#pragma unroll
        for (int i = 0; i < 4; ++i)
#pragma unroll
            for (int j = 0; j < 4; ++j) {
                int m = m0 + wm + i * 16 + quad * 4;   // row in [0,8192)
                int n = n0 + wn + j * 16 + row16;      // feature e
                int b = m >> 11, s = m & 2047;
                union { ushort4 u4; u16 h[4]; } o;
#pragma unroll
                for (int r = 0; r < 4; ++r) o.h[r] = f2bf(acc[i][j][r]);
                *(ushort4*)(Vt + ((size_t)b * 1024 + n) * 2048 + s) = o.u4;
            }
    }
}

// Scores: S[b][i][j] = Q[b,i,:]·K[b,j,:] / 32, lower-triangular tiles only.
// grid (136, B)
__global__ __launch_bounds__(256) void k_gemm_scores(const u16* __restrict__ Q,
                                                     const u16* __restrict__ Kb,
                                                     u16* __restrict__ Sb) {
    __shared__ u16 smem[128 * 64];
    int t = blockIdx.x, b = blockIdx.y;
    int mt = 0;
    while ((mt + 1) * (mt + 2) / 2 <= t) ++mt;
    int nt = t - mt * (mt + 1) / 2;
    const u16* Qp = Q + (size_t)b * 2048 * 1024 + (size_t)mt * 128 * 1024;
    const u16* Kp = Kb + (size_t)b * 2048 * 1024 + (size_t)nt * 128 * 1024;
    u16* Sp = Sb + (size_t)b * 2048 * 2048;
    f32x4 acc[4][4];
    gemm_core_nt(Qp, Kp, 1024, 1024, 1024, smem, acc);
    const int tid = threadIdx.x, wave = tid >> 6;
    const int wm = (wave >> 1) * 64, wn = (wave & 1) * 64;
    __syncthreads();
    epi_bf16(acc, smem,
             Sp + (size_t)(mt * 128 + wm) * 2048 + nt * 128 + wn, 2048, 0.03125f);
}

// PV: O[b][i][e] = sum_j P[b][i][j] * V[b][j][e], k-extent (mt+1)*128.
// grid (8, 16, B); longest-K blocks first (mt reversed) to shrink the tail.
__global__ __launch_bounds__(256) void k_gemm_pv(const u16* __restrict__ P,
                                                 const u16* __restrict__ Vt,
                                                 float* __restrict__ O) {
    __shared__ u16 smem[128 * 64];
    const int nt = blockIdx.x, mt = 15 - blockIdx.y, b = blockIdx.z;
    const u16* Pp = P + (size_t)b * 2048 * 2048 + (size_t)mt * 128 * 2048;
    const u16* Vp = Vt + (size_t)b * 1024 * 2048 + (size_t)nt * 128 * 2048;
    f32x4 acc[4][4];
    gemm_core_nt(Pp, Vp, 2048, 2048, (mt + 1) * 128, smem, acc);
    float* Op = O + (size_t)b * 2048 * 1024;
    const int tid = threadIdx.x, wave = tid >> 6, lane = tid & 63;
    const int wm = (wave >> 1) * 64, wn = (wave & 1) * 64;
    const int row16 = lane & 15, quad = lane >> 4;
#pragma unroll
    for (int i = 0; i < 4; ++i)
#pragma unroll
        for (int j = 0; j < 4; ++j) {
            int m = mt * 128 + wm + i * 16 + quad * 4;
            int n = nt * 128 + wn + j * 16 + row16;
#pragma unroll
            for (int r = 0; r < 4; ++r)
                Op[(size_t)(m + r) * 1024 + n] = acc[i][j][r];
        }
}

// ---------------- softmax: one wave per row ----------------
// grid (512, B), 256 thr = 4 waves = 4 rows. Row i: valid length L=i+1,
// zero out [L, Lpad), Lpad = ((i>>7)+1)*128 (== PV's k-extent).
__global__ __launch_bounds__(256) void k_softmax(u16* __restrict__ Sb) {
    const int wave = threadIdx.x >> 6, lane = threadIdx.x & 63;
    const int i = blockIdx.x * 4 + wave;
    u16* row = Sb + ((size_t)blockIdx.y * 2048 + i) * 2048;
    const int L = i + 1;
    const int Lpad = ((i >> 7) + 1) << 7;

    float v[32];
    float mx = -3.0e38f;
#pragma unroll
    for (int c = 0; c < 4; ++c) {
        int j0 = c * 512 + lane * 8;
        if (j0 + 8 <= L) {
            int4 p = *(const int4*)(row + j0);
            const u16* h = (const u16*)&p;
#pragma unroll
            for (int k = 0; k < 8; ++k) {
                float t = bf2f(h[k]);
                v[c * 8 + k] = t;
                mx = fmaxf(mx, t);
            }
        } else {
#pragma unroll
            for (int k = 0; k < 8; ++k) {
                int j = j0 + k;
                float t = (j < L) ? bf2f(row[j]) : -3.0e38f;
                v[c * 8 + k] = t;
                mx = fmaxf(mx, t);
            }
        }
    }
#pragma unroll
    for (int off = 32; off > 0; off >>= 1) mx = fmaxf(mx, __shfl_xor(mx, off));

    float sum = 0.f;
#pragma unroll
    for (int c = 0; c < 32; ++c) {
        float e = __expf(v[c] - mx);   // masked entries: exp(-huge) = 0
        v[c] = e;
        sum += e;
    }
#pragma unroll
    for (int off = 32; off > 0; off >>= 1) sum += __shfl_xor(sum, off);
    const float inv = 1.0f / sum;

#pragma unroll
    for (int c = 0; c < 4; ++c) {
        int j0 = c * 512 + lane * 8;
        if (j0 >= Lpad) continue;
        if (j0 + 8 <= L) {
            union { int4 p; u16 h[8]; } o;
#pragma unroll
            for (int k = 0; k < 8; ++k) o.h[k] = f2bf(v[c * 8 + k] * inv);
            *(int4*)(row + j0) = o.p;
        } else {
#pragma unroll
            for (int k = 0; k < 8; ++k) {
                int j = j0 + k;
                if (j < L) row[j] = f2bf(v[c * 8 + k] * inv);
                else if (j < Lpad) row[j] = 0;
            }
        }
    }
}

// ---------------- launcher ----------------
extern "C" void kernel_launch(void* const* d_in, const int* in_sizes, int n_in,
                              void* d_out, int out_size, void* d_ws, size_t ws_size,
                              hipStream_t stream) {
    const float* x  = (const float*)d_in[0];
    const float* Wq = (const float*)d_in[1];
    const float* Wk = (const float*)d_in[2];
    const float* Wv = (const float*)d_in[3];
    float* out = (float*)d_out;
    char* ws = (char*)d_ws;

    // workspace layout (102 MB total)
    u16* xb  = (u16*)(ws);                          // 16 MB: x bf16 [8192,1024]
    u16* Wt3 = (u16*)(ws + (16u << 20));            //  6 MB: [Wq^T;Wk^T;Wv^T] bf16 [3072,1024]
    u16* Qb  = (u16*)(ws + (22u << 20));            // 16 MB: Q bf16 [8192,1024]
    u16* Kb  = (u16*)(ws + (38u << 20));            // 16 MB: K bf16
    u16* Vt  = (u16*)(ws + (54u << 20));            // 16 MB: V^T bf16 [B,1024,2048]
    u16* Sb  = (u16*)(ws + (70u << 20));            // 32 MB: scores/P bf16 [B,2048,2048]

    k_cvt_x<<<4096, 256, 0, stream>>>(x, xb, 8192 * 1024);
    k_cvt_w3<<<dim3(32, 32, 3), 256, 0, stream>>>(Wq, Wk, Wv, Wt3);

    k_gemm_proj<<<dim3(24, 64), 256, 0, stream>>>(xb, Wt3, Qb, Kb, Vt);

    k_gemm_scores<<<dim3(136, 4), 256, 0, stream>>>(Qb, Kb, Sb);
    k_softmax<<<dim3(512, 4), 256, 0, stream>>>(Sb);
    k_gemm_pv<<<dim3(8, 16, 4), 256, 0, stream>>>(Sb, Vt, out);
}

// Round 4
// 247.206 us; speedup vs baseline: 1.1609x; 1.0973x over previous
//
#include <hip/hip_runtime.h>

typedef unsigned short u16;
typedef __bf16 bf16x8_v __attribute__((ext_vector_type(8)));
typedef float f32x4 __attribute__((ext_vector_type(4)));

// ---------- bf16 helpers ----------
__device__ __forceinline__ u16 f2bf(float f) {
    unsigned u = __float_as_uint(f);
    unsigned r = u + 0x7fffu + ((u >> 16) & 1u);   // RNE; inputs finite
    return (u16)(r >> 16);
}
__device__ __forceinline__ float bf2f(u16 h) {
    return __uint_as_float(((unsigned)h) << 16);
}

// async global->LDS, 16B per lane; lds dst = wave-uniform base + lane*16
__device__ __forceinline__ void gll16(const u16* g, u16* l) {
    __builtin_amdgcn_global_load_lds(
        (const __attribute__((address_space(1))) void*)g,
        (__attribute__((address_space(3))) void*)l, 16, 0, 0);
}

#define EXP_SHIFT 12.0f   // fixed-shift softmax: e = exp(score - SHIFT); safe for score in (-67, +100)

// ---------------- conversion kernels ----------------
__global__ __launch_bounds__(256) void k_cvt_x(const float* __restrict__ x,
                                               u16* __restrict__ y, int n) {
    int i = (blockIdx.x * 256 + threadIdx.x) * 8;
    if (i < n) {
        float4 a = *(const float4*)(x + i);
        float4 b = *(const float4*)(x + i + 4);
        union { int4 p; u16 h[8]; } o;
        o.h[0] = f2bf(a.x); o.h[1] = f2bf(a.y); o.h[2] = f2bf(a.z); o.h[3] = f2bf(a.w);
        o.h[4] = f2bf(b.x); o.h[5] = f2bf(b.y); o.h[6] = f2bf(b.z); o.h[7] = f2bf(b.w);
        *(int4*)(y + i) = o.p;
    }
}

// W [1024,1024] fp32 row-major -> Wt3 slice bf16 with Wt[n][k] = W[k][n].
// grid (32, 32, 3): z selects Wq/Wk/Wv.
__global__ __launch_bounds__(256) void k_cvt_w3(const float* __restrict__ Wq,
                                                const float* __restrict__ Wk,
                                                const float* __restrict__ Wv,
                                                u16* __restrict__ Wt3) {
    __shared__ float tile[32][33];
    const int z = blockIdx.z;
    const float* W = (z == 0) ? Wq : (z == 1) ? Wk : Wv;
    u16* Wt = Wt3 + (size_t)z * 1024 * 1024;
    int bx = blockIdx.x;            // n-tile
    int by = blockIdx.y;            // k-tile
    int tx = threadIdx.x & 31;
    int ty = threadIdx.x >> 5;      // 0..7
#pragma unroll
    for (int r = 0; r < 4; ++r)
        tile[ty + r * 8][tx] = W[(by * 32 + ty + r * 8) * 1024 + bx * 32 + tx];
    __syncthreads();
#pragma unroll
    for (int r = 0; r < 4; ++r)
        Wt[(bx * 32 + ty + r * 8) * 1024 + by * 32 + tx] =
            f2bf(tile[tx][ty + r * 8]);
}

// ---------------- GEMM core: NT form, global_load_lds staging ----------------
// C[m][n] = sum_k A[m][k] * Bnt[n][k]; A,Bnt bf16 row-major.
// Block 256 thr = 4 waves (2x2), tile 128x128, BK=32, acc 4x4 per wave.
// smem: 16 KB (As 8 KB | Bs 8 KB), reused by the epilogue afterwards.
__device__ __forceinline__ void gemm_core_nt(const u16* __restrict__ A,   // + m0*lda
                                             const u16* __restrict__ B,   // + n0*ldb
                                             int lda, int ldb, int kLen,
                                             u16* smem, f32x4 acc[4][4]) {
    u16* As = smem;
    u16* Bs = smem + 128 * 32;
    const int tid = threadIdx.x;
    const int wave = tid >> 6;
    const int lane = tid & 63;
    // staging: chunk c=tid covers LDS bytes [c*16, c*16+16) == row (c>>2), col (c&3)*8
    const int r0 = tid >> 2, o0 = (tid & 3) * 8;
    const int r1 = r0 + 64;                 // chunk tid+256
    u16* AsW0 = As + wave * 512;            // lane*16B appended by HW
    u16* AsW1 = As + 2048 + wave * 512;
    u16* BsW0 = Bs + wave * 512;
    u16* BsW1 = Bs + 2048 + wave * 512;

    const int wm = (wave >> 1) * 64;
    const int wn = (wave & 1) * 64;
    const int row16 = lane & 15;
    const int quad = lane >> 4;

#pragma unroll
    for (int i = 0; i < 4; ++i)
#pragma unroll
        for (int j = 0; j < 4; ++j) {
            f32x4 z = {0.f, 0.f, 0.f, 0.f};
            acc[i][j] = z;
        }

    const u16* Ag0 = A + r0 * lda + o0;
    const u16* Ag1 = A + r1 * lda + o0;
    const u16* Bg0 = B + r0 * ldb + o0;
    const u16* Bg1 = B + r1 * ldb + o0;

    const int ktiles = kLen >> 5;
    for (int kt = 0; kt < ktiles; ++kt) {
        __syncthreads();                    // all waves done reading prev tile
        gll16(Ag0 + kt * 32, AsW0);
        gll16(Ag1 + kt * 32, AsW1);
        gll16(Bg0 + kt * 32, BsW0);
        gll16(Bg1 + kt * 32, BsW1);
        __syncthreads();                    // vmcnt drained before barrier
        bf16x8_v af[4], bfv[4];
#pragma unroll
        for (int i = 0; i < 4; ++i)
            af[i] = *(const bf16x8_v*)(As + (wm + i * 16 + row16) * 32 + quad * 8);
#pragma unroll
        for (int j = 0; j < 4; ++j)
            bfv[j] = *(const bf16x8_v*)(Bs + (wn + j * 16 + row16) * 32 + quad * 8);
#pragma unroll
        for (int i = 0; i < 4; ++i)
#pragma unroll
            for (int j = 0; j < 4; ++j)
                acc[i][j] = __builtin_amdgcn_mfma_f32_16x16x32_bf16(
                    af[i], bfv[j], acc[i][j], 0, 0, 0);
    }
}

// Coalesced bf16 epilogue: transpose this wave's 64x64 tile through its 4 KB
// LDS slice, store as dwordx4 (64B row segments). Caller must __syncthreads()
// after the main loop before calling (smem is being repurposed).
__device__ __forceinline__ void epi_bf16(const f32x4 acc[4][4], u16* smem,
                                         u16* __restrict__ g, int ldg) {
    const int tid = threadIdx.x;
    const int wave = tid >> 6, lane = tid & 63;
    const int row16 = lane & 15, quad = lane >> 4;
    u16* Ts = smem + wave * 2048;           // 64 rows x 32 cols (u16)
#pragma unroll
    for (int jh = 0; jh < 2; ++jh) {        // two 64x32 halves (cols jh*32..)
#pragma unroll
        for (int i = 0; i < 4; ++i)
#pragma unroll
            for (int jj = 0; jj < 2; ++jj) {
                const int j = jh * 2 + jj;
#pragma unroll
                for (int r = 0; r < 4; ++r)
                    Ts[(i * 16 + quad * 4 + r) * 32 + jj * 16 + row16] =
                        f2bf(acc[i][j][r]);
            }
        // per-wave DS ordering guarantees write->read visibility (same wave)
#pragma unroll
        for (int s = 0; s < 4; ++s) {
            const int row = s * 16 + (lane >> 2);
            int4 val = *(const int4*)(Ts + row * 32 + (lane & 3) * 8);
            *(int4*)(g + (size_t)row * ldg + jh * 32 + (lane & 3) * 8) = val;
        }
    }
}

// ---------------- fused QKV projection ----------------
// Wt3 = [Wq^T ; Wk^T ; Wv^T] bf16 [3072,1024]. grid (24, 64).
// n0g<1024 -> Q, <2048 -> K, else V written transposed Vt[b][e][s].
__global__ __launch_bounds__(256, 3) void k_gemm_proj(const u16* __restrict__ X,
                                                      const u16* __restrict__ Wt3,
                                                      u16* __restrict__ Qb,
                                                      u16* __restrict__ Kb,
                                                      u16* __restrict__ Vt) {
    __shared__ u16 smem[128 * 64];
    const int n0g = blockIdx.x * 128, m0 = blockIdx.y * 128;
    f32x4 acc[4][4];
    gemm_core_nt(X + (size_t)m0 * 1024, Wt3 + (size_t)n0g * 1024, 1024, 1024, 1024,
                 smem, acc);
    const int tid = threadIdx.x, wave = tid >> 6, lane = tid & 63;
    const int wm = (wave >> 1) * 64, wn = (wave & 1) * 64;
    const int row16 = lane & 15, quad = lane >> 4;
    if (n0g < 2048) {
        u16* Y = (n0g < 1024) ? Qb : Kb;
        const int n0 = n0g & 1023;
        __syncthreads();
        epi_bf16(acc, smem, Y + (size_t)(m0 + wm) * 1024 + n0 + wn, 1024);
    } else {
        const int n0 = n0g - 2048;
#pragma unroll
        for (int i = 0; i < 4; ++i)
#pragma unroll
            for (int j = 0; j < 4; ++j) {
                int m = m0 + wm + i * 16 + quad * 4;   // row in [0,8192)
                int n = n0 + wn + j * 16 + row16;      // feature e
                int b = m >> 11, s = m & 2047;
                union { ushort4 u4; u16 h[4]; } o;
#pragma unroll
                for (int r = 0; r < 4; ++r) o.h[r] = f2bf(acc[i][j][r]);
                *(ushort4*)(Vt + ((size_t)b * 1024 + n) * 2048 + s) = o.u4;
            }
    }
}

// Scores + fused unnormalized exp: P'[b][i][j] = exp(q.k/32 - SHIFT) for j<=i,
// 0 for j>i (in-tile mask); accumulates row sums into Srow[b*2048+i] via
// atomicAdd. Lower-triangular tiles only; grid (136, B).
__global__ __launch_bounds__(256, 3) void k_gemm_scores(const u16* __restrict__ Q,
                                                        const u16* __restrict__ Kb,
                                                        u16* __restrict__ Sb,
                                                        float* __restrict__ Srow) {
    __shared__ u16 smem[128 * 64];
    int t = blockIdx.x, b = blockIdx.y;
    int mt = 0;
    while ((mt + 1) * (mt + 2) / 2 <= t) ++mt;
    int nt = t - mt * (mt + 1) / 2;
    const u16* Qp = Q + (size_t)b * 2048 * 1024 + (size_t)mt * 128 * 1024;
    const u16* Kp = Kb + (size_t)b * 2048 * 1024 + (size_t)nt * 128 * 1024;
    u16* Sp = Sb + (size_t)b * 2048 * 2048;
    f32x4 acc[4][4];
    gemm_core_nt(Qp, Kp, 1024, 1024, 1024, smem, acc);
    const int tid = threadIdx.x, wave = tid >> 6, lane = tid & 63;
    const int wm = (wave >> 1) * 64, wn = (wave & 1) * 64;
    const int row16 = lane & 15, quad = lane >> 4;
    const int mBase = mt * 128 + wm;            // + i*16 + quad*4 + r
    const int nBase = nt * 128 + wn;            // + jh*32 + jj*16 + row16
    u16* Ts = smem + wave * 2048;               // 64x32 u16 transpose slice
    float rs[4][4];
#pragma unroll
    for (int i = 0; i < 4; ++i)
#pragma unroll
        for (int r = 0; r < 4; ++r) rs[i][r] = 0.f;

    __syncthreads();                            // done with As/Bs
#pragma unroll
    for (int jh = 0; jh < 2; ++jh) {
#pragma unroll
        for (int i = 0; i < 4; ++i)
#pragma unroll
            for (int jj = 0; jj < 2; ++jj) {
                const int j = jh * 2 + jj;
                const int n = nBase + jh * 32 + jj * 16 + row16;
#pragma unroll
                for (int r = 0; r < 4; ++r) {
                    const int m = mBase + i * 16 + quad * 4 + r;
                    float e = 0.f;
                    if (n <= m)
                        e = __expf(acc[i][j][r] * 0.03125f - EXP_SHIFT);
                    rs[i][r] += e;
                    Ts[(i * 16 + quad * 4 + r) * 32 + jj * 16 + row16] = f2bf(e);
                }
            }
#pragma unroll
        for (int s = 0; s < 4; ++s) {
            const int row = s * 16 + (lane >> 2);
            int4 val = *(const int4*)(Ts + row * 32 + (lane & 3) * 8);
            *(int4*)(Sp + (size_t)(mt * 128 + wm + row) * 2048 +
                     nt * 128 + wn + jh * 32 + (lane & 3) * 8) = val;
        }
    }
    // row-sum: butterfly over the 16 row16 lanes (covers this wave's 64 cols),
    // then one atomicAdd per row from the row16==0 lanes.
    float* Sr = Srow + (size_t)b * 2048;
#pragma unroll
    for (int i = 0; i < 4; ++i)
#pragma unroll
        for (int r = 0; r < 4; ++r) {
            float s = rs[i][r];
#pragma unroll
            for (int off = 1; off < 16; off <<= 1) s += __shfl_xor(s, off);
            if (row16 == 0)
                atomicAdd(Sr + mBase + i * 16 + quad * 4 + r, s);
        }
}

// PV: O[b][i][e] = (1/Srow[b,i]) * sum_j P'[b][i][j] * V[b][j][e].
// k-extent (mt+1)*128; grid (8, 16, B), longest-K first (mt reversed).
__global__ __launch_bounds__(256, 3) void k_gemm_pv(const u16* __restrict__ P,
                                                    const u16* __restrict__ Vt,
                                                    const float* __restrict__ Srow,
                                                    float* __restrict__ O) {
    __shared__ u16 smem[128 * 64];
    const int nt = blockIdx.x, mt = 15 - blockIdx.y, b = blockIdx.z;
    const u16* Pp = P + (size_t)b * 2048 * 2048 + (size_t)mt * 128 * 2048;
    const u16* Vp = Vt + (size_t)b * 1024 * 2048 + (size_t)nt * 128 * 2048;
    f32x4 acc[4][4];
    gemm_core_nt(Pp, Vp, 2048, 2048, (mt + 1) * 128, smem, acc);
    float* Op = O + (size_t)b * 2048 * 1024;
    const float* Sr = Srow + (size_t)b * 2048;
    const int tid = threadIdx.x, wave = tid >> 6, lane = tid & 63;
    const int wm = (wave >> 1) * 64, wn = (wave & 1) * 64;
    const int row16 = lane & 15, quad = lane >> 4;
    float inv[4][4];
#pragma unroll
    for (int i = 0; i < 4; ++i)
#pragma unroll
        for (int r = 0; r < 4; ++r)
            inv[i][r] = 1.0f / Sr[mt * 128 + wm + i * 16 + quad * 4 + r];
#pragma unroll
    for (int i = 0; i < 4; ++i)
#pragma unroll
        for (int j = 0; j < 4; ++j) {
            int m = mt * 128 + wm + i * 16 + quad * 4;
            int n = nt * 128 + wn + j * 16 + row16;
#pragma unroll
            for (int r = 0; r < 4; ++r)
                Op[(size_t)(m + r) * 1024 + n] = acc[i][j][r] * inv[i][r];
        }
}

// ---------------- launcher ----------------
extern "C" void kernel_launch(void* const* d_in, const int* in_sizes, int n_in,
                              void* d_out, int out_size, void* d_ws, size_t ws_size,
                              hipStream_t stream) {
    const float* x  = (const float*)d_in[0];
    const float* Wq = (const float*)d_in[1];
    const float* Wk = (const float*)d_in[2];
    const float* Wv = (const float*)d_in[3];
    float* out = (float*)d_out;
    char* ws = (char*)d_ws;

    // workspace layout (102 MB total)
    u16* xb  = (u16*)(ws);                          // 16 MB: x bf16 [8192,1024]
    u16* Wt3 = (u16*)(ws + (16u << 20));            //  6 MB: [Wq^T;Wk^T;Wv^T] bf16 [3072,1024]
    u16* Qb  = (u16*)(ws + (22u << 20));            // 16 MB: Q bf16 [8192,1024]
    u16* Kb  = (u16*)(ws + (38u << 20));            // 16 MB: K bf16
    u16* Vt  = (u16*)(ws + (54u << 20));            // 16 MB: V^T bf16 [B,1024,2048]
    u16* Sb  = (u16*)(ws + (70u << 20));            // 32 MB: P' bf16 [B,2048,2048]
    // Srow aliases xb's first 32 KB: xb is only read by k_gemm_proj, which
    // completes before the memset below (stream order).
    float* Srow = (float*)ws;                       // 32 KB: row sums [B*2048]

    k_cvt_x<<<4096, 256, 0, stream>>>(x, xb, 8192 * 1024);
    k_cvt_w3<<<dim3(32, 32, 3), 256, 0, stream>>>(Wq, Wk, Wv, Wt3);

    k_gemm_proj<<<dim3(24, 64), 256, 0, stream>>>(xb, Wt3, Qb, Kb, Vt);

    hipMemsetAsync(Srow, 0, 8192 * sizeof(float), stream);
    k_gemm_scores<<<dim3(136, 4), 256, 0, stream>>>(Qb, Kb, Sb, Srow);
    k_gemm_pv<<<dim3(8, 16, 4), 256, 0, stream>>>(Sb, Vt, Srow, out);
}

// Round 5
// 225.760 us; speedup vs baseline: 1.2712x; 1.0950x over previous
//
#include <hip/hip_runtime.h>

typedef unsigned short u16;
typedef __bf16 bf16x8_v __attribute__((ext_vector_type(8)));
typedef float f32x4 __attribute__((ext_vector_type(4)));

// ---------- bf16 helpers ----------
__device__ __forceinline__ u16 f2bf(float f) {
    unsigned u = __float_as_uint(f);
    unsigned r = u + 0x7fffu + ((u >> 16) & 1u);   // RNE; inputs finite
    return (u16)(r >> 16);
}
__device__ __forceinline__ float bf2f(u16 h) {
    return __uint_as_float(((unsigned)h) << 16);
}

// async global->LDS, 16B per lane; lds dst = WAVE-UNIFORM base, HW adds lane*16
__device__ __forceinline__ void gll16(const u16* g, u16* l) {
    __builtin_amdgcn_global_load_lds(
        (const __attribute__((address_space(1))) void*)g,
        (__attribute__((address_space(3))) void*)l, 16, 0, 0);
}

#define EXP_SHIFT 12.0f   // fixed-shift softmax: e = exp(score - SHIFT)

// ---------------- conversion kernels ----------------
__global__ __launch_bounds__(256) void k_cvt_x(const float* __restrict__ x,
                                               u16* __restrict__ y, int n) {
    int i = (blockIdx.x * 256 + threadIdx.x) * 8;
    if (i < n) {
        float4 a = *(const float4*)(x + i);
        float4 b = *(const float4*)(x + i + 4);
        union { int4 p; u16 h[8]; } o;
        o.h[0] = f2bf(a.x); o.h[1] = f2bf(a.y); o.h[2] = f2bf(a.z); o.h[3] = f2bf(a.w);
        o.h[4] = f2bf(b.x); o.h[5] = f2bf(b.y); o.h[6] = f2bf(b.z); o.h[7] = f2bf(b.w);
        *(int4*)(y + i) = o.p;
    }
}

// W [1024,1024] fp32 row-major -> Wt3 slice bf16 with Wt[n][k] = W[k][n].
__global__ __launch_bounds__(256) void k_cvt_w3(const float* __restrict__ Wq,
                                                const float* __restrict__ Wk,
                                                const float* __restrict__ Wv,
                                                u16* __restrict__ Wt3) {
    __shared__ float tile[32][33];
    const int z = blockIdx.z;
    const float* W = (z == 0) ? Wq : (z == 1) ? Wk : Wv;
    u16* Wt = Wt3 + (size_t)z * 1024 * 1024;
    int bx = blockIdx.x;
    int by = blockIdx.y;
    int tx = threadIdx.x & 31;
    int ty = threadIdx.x >> 5;
#pragma unroll
    for (int r = 0; r < 4; ++r)
        tile[ty + r * 8][tx] = W[(by * 32 + ty + r * 8) * 1024 + bx * 32 + tx];
    __syncthreads();
#pragma unroll
    for (int r = 0; r < 4; ++r)
        Wt[(bx * 32 + ty + r * 8) * 1024 + by * 32 + tx] =
            f2bf(tile[tx][ty + r * 8]);
}

// ---------------- GEMM core: NT, BK=64, XOR-swizzled LDS ----------------
// C[m][n] = sum_k A[m][k] * Bnt[n][k]. 4 waves (2x2), tile 128x128, BK=64.
// LDS: As/Bs 128x64 u16 (16 KB each). Swizzle: LDS 16B-chunk position p of
// row r holds global chunk p^(r&7) -> fragment ds_read_b128 spreads over all
// 32 banks (was 8-way conflicted at stride-64B).
__device__ __forceinline__ void gemm_core_nt(const u16* __restrict__ A,
                                             const u16* __restrict__ B,
                                             int lda, int ldb, int kLen,
                                             u16* smem, f32x4 acc[4][4]) {
    u16* As = smem;
    u16* Bs = smem + 128 * 64;
    const int tid = threadIdx.x;
    const int wave = tid >> 6;
    const int lane = tid & 63;
    const int rowA = tid >> 3;                    // staging row (u=0), 0..31
    const int kcs  = (tid & 7) ^ (rowA & 7);      // swizzled global chunk
    const int row16 = lane & 15;
    const int quad = lane >> 4;
    const int sw = row16 & 7;                     // read-side swizzle
    const int wm = (wave >> 1) * 64;
    const int wn = (wave & 1) * 64;

#pragma unroll
    for (int i = 0; i < 4; ++i)
#pragma unroll
        for (int j = 0; j < 4; ++j) {
            f32x4 z = {0.f, 0.f, 0.f, 0.f};
            acc[i][j] = z;
        }

    const u16* Ag[4]; const u16* Bg[4];
    u16 *AsB[4], *BsB[4];
#pragma unroll
    for (int u = 0; u < 4; ++u) {
        Ag[u] = A + (size_t)(u * 32 + rowA) * lda + kcs * 8;
        Bg[u] = B + (size_t)(u * 32 + rowA) * ldb + kcs * 8;
        AsB[u] = As + (u * 256 + wave * 64) * 8;  // wave-uniform; HW += lane*16
        BsB[u] = Bs + (u * 256 + wave * 64) * 8;
    }

    const int ktiles = kLen >> 6;
    for (int kt = 0; kt < ktiles; ++kt) {
        __syncthreads();                          // prev tile fully consumed
#pragma unroll
        for (int u = 0; u < 4; ++u) gll16(Ag[u] + kt * 64, AsB[u]);
#pragma unroll
        for (int u = 0; u < 4; ++u) gll16(Bg[u] + kt * 64, BsB[u]);
        __syncthreads();                          // vmcnt drained before barrier
#pragma unroll
        for (int h = 0; h < 2; ++h) {
            bf16x8_v af[4], bfv[4];
            const int cp = (h * 4 + quad);
#pragma unroll
            for (int i = 0; i < 4; ++i)
                af[i] = *(const bf16x8_v*)(As + (wm + i * 16 + row16) * 64 +
                                           (cp ^ sw) * 8);
#pragma unroll
            for (int j = 0; j < 4; ++j)
                bfv[j] = *(const bf16x8_v*)(Bs + (wn + j * 16 + row16) * 64 +
                                            (cp ^ sw) * 8);
#pragma unroll
            for (int i = 0; i < 4; ++i)
#pragma unroll
                for (int j = 0; j < 4; ++j)
                    acc[i][j] = __builtin_amdgcn_mfma_f32_16x16x32_bf16(
                        af[i], bfv[j], acc[i][j], 0, 0, 0);
        }
    }
}

// Coalesced bf16 epilogue (row-major out): per-wave 64x64 tile through 4 KB
// LDS slice, dwordx4 stores (64B row runs). Requires __syncthreads() first.
__device__ __forceinline__ void epi_bf16(const f32x4 acc[4][4], u16* smem,
                                         u16* __restrict__ g, int ldg) {
    const int tid = threadIdx.x;
    const int wave = tid >> 6, lane = tid & 63;
    const int row16 = lane & 15, quad = lane >> 4;
    u16* Ts = smem + wave * 2048;           // 64 rows x 32 cols (u16)
#pragma unroll
    for (int jh = 0; jh < 2; ++jh) {
#pragma unroll
        for (int i = 0; i < 4; ++i)
#pragma unroll
            for (int jj = 0; jj < 2; ++jj) {
                const int j = jh * 2 + jj;
#pragma unroll
                for (int r = 0; r < 4; ++r)
                    Ts[(i * 16 + quad * 4 + r) * 32 + jj * 16 + row16] =
                        f2bf(acc[i][j][r]);
            }
        // same-wave DS ordering: write->read visible without barrier
#pragma unroll
        for (int s = 0; s < 4; ++s) {
            const int row = s * 16 + (lane >> 2);
            int4 val = *(const int4*)(Ts + row * 32 + (lane & 3) * 8);
            *(int4*)(g + (size_t)row * ldg + jh * 32 + (lane & 3) * 8) = val;
        }
    }
}

// V-transposed epilogue: wave 64x64 tile -> Vt[e][s] with 16B runs along s.
// Two passes of 32 n-rows; per-wave slice 32x72 u16 (9 KB, pad for banks).
__device__ __forceinline__ void epi_vt(const f32x4 acc[4][4], u16* smem,
                                       u16* __restrict__ Vt, int m0w, int n0w) {
    const int tid = threadIdx.x;
    const int wave = tid >> 6, lane = tid & 63;
    const int row16 = lane & 15, quad = lane >> 4;
    const int b = m0w >> 11;                 // tile never crosses batch bound
    const int sBase = m0w & 2047;
    u16* Ts = smem + wave * 4608;            // 32 rows x 72 cols (u16)
#pragma unroll
    for (int p = 0; p < 2; ++p) {
#pragma unroll
        for (int i = 0; i < 4; ++i)
#pragma unroll
            for (int jj = 0; jj < 2; ++jj) {
                const int j = p * 2 + jj;
                union { unsigned long long d; u16 h[4]; } o;
#pragma unroll
                for (int r = 0; r < 4; ++r) o.h[r] = f2bf(acc[i][j][r]);
                *(unsigned long long*)(Ts + (jj * 16 + row16) * 72 +
                                       i * 16 + quad * 4) = o.d;
            }
        // same-wave DS ordering
#pragma unroll
        for (int rr = 0; rr < 4; ++rr) {
            const int ln = rr * 8 + (lane >> 3);
            const int ck = lane & 7;
            int4 val = *(const int4*)(Ts + ln * 72 + ck * 8);
            const int n = n0w + p * 32 + ln;
            *(int4*)(Vt + ((size_t)b * 1024 + n) * 2048 + sBase + ck * 8) = val;
        }
    }
}

// ---------------- fused QKV projection ----------------
// grid (24, 64). n0g<1024 -> Q, <2048 -> K, else V transposed.
__global__ __launch_bounds__(256, 3) void k_gemm_proj(const u16* __restrict__ X,
                                                      const u16* __restrict__ Wt3,
                                                      u16* __restrict__ Qb,
                                                      u16* __restrict__ Kb,
                                                      u16* __restrict__ Vt) {
    __shared__ u16 smem[18432];              // 36 KB: core 32 KB | epi_vt 36 KB
    const int n0g = blockIdx.x * 128, m0 = blockIdx.y * 128;
    f32x4 acc[4][4];
    gemm_core_nt(X + (size_t)m0 * 1024, Wt3 + (size_t)n0g * 1024, 1024, 1024, 1024,
                 smem, acc);
    const int tid = threadIdx.x, wave = tid >> 6;
    const int wm = (wave >> 1) * 64, wn = (wave & 1) * 64;
    __syncthreads();                         // smem repurposed by epilogues
    if (n0g < 2048) {
        u16* Y = (n0g < 1024) ? Qb : Kb;
        const int n0 = n0g & 1023;
        epi_bf16(acc, smem, Y + (size_t)(m0 + wm) * 1024 + n0 + wn, 1024);
    } else {
        epi_vt(acc, smem, Vt, m0 + wm, (n0g - 2048) + wn);
    }
}

// Scores + fused unnormalized exp; lower-triangular tiles only; grid (136, B).
__global__ __launch_bounds__(256, 3) void k_gemm_scores(const u16* __restrict__ Q,
                                                        const u16* __restrict__ Kb,
                                                        u16* __restrict__ Sb,
                                                        float* __restrict__ Srow) {
    __shared__ u16 smem[16384];              // 32 KB
    int t = blockIdx.x, b = blockIdx.y;
    int mt = 0;
    while ((mt + 1) * (mt + 2) / 2 <= t) ++mt;
    int nt = t - mt * (mt + 1) / 2;
    const u16* Qp = Q + (size_t)b * 2048 * 1024 + (size_t)mt * 128 * 1024;
    const u16* Kp = Kb + (size_t)b * 2048 * 1024 + (size_t)nt * 128 * 1024;
    u16* Sp = Sb + (size_t)b * 2048 * 2048;
    f32x4 acc[4][4];
    gemm_core_nt(Qp, Kp, 1024, 1024, 1024, smem, acc);
    const int tid = threadIdx.x, wave = tid >> 6, lane = tid & 63;
    const int wm = (wave >> 1) * 64, wn = (wave & 1) * 64;
    const int row16 = lane & 15, quad = lane >> 4;
    const int mBase = mt * 128 + wm;
    const int nBase = nt * 128 + wn;
    u16* Ts = smem + wave * 2048;
    float rs[4][4];
#pragma unroll
    for (int i = 0; i < 4; ++i)
#pragma unroll
        for (int r = 0; r < 4; ++r) rs[i][r] = 0.f;

    __syncthreads();
#pragma unroll
    for (int jh = 0; jh < 2; ++jh) {
#pragma unroll
        for (int i = 0; i < 4; ++i)
#pragma unroll
            for (int jj = 0; jj < 2; ++jj) {
                const int j = jh * 2 + jj;
                const int n = nBase + jh * 32 + jj * 16 + row16;
#pragma unroll
                for (int r = 0; r < 4; ++r) {
                    const int m = mBase + i * 16 + quad * 4 + r;
                    float e = 0.f;
                    if (n <= m)
                        e = __expf(acc[i][j][r] * 0.03125f - EXP_SHIFT);
                    rs[i][r] += e;
                    Ts[(i * 16 + quad * 4 + r) * 32 + jj * 16 + row16] = f2bf(e);
                }
            }
#pragma unroll
        for (int s = 0; s < 4; ++s) {
            const int row = s * 16 + (lane >> 2);
            int4 val = *(const int4*)(Ts + row * 32 + (lane & 3) * 8);
            *(int4*)(Sp + (size_t)(mBase + row) * 2048 +
                     nBase + jh * 32 + (lane & 3) * 8) = val;
        }
    }
    float* Sr = Srow + (size_t)b * 2048;
#pragma unroll
    for (int i = 0; i < 4; ++i)
#pragma unroll
        for (int r = 0; r < 4; ++r) {
            float s = rs[i][r];
#pragma unroll
            for (int off = 1; off < 16; off <<= 1) s += __shfl_xor(s, off);
            if (row16 == 0)
                atomicAdd(Sr + mBase + i * 16 + quad * 4 + r, s);
        }
}

// PV: O = (1/Srow) * P'.V; k-extent (mt+1)*128; grid (8, 16, B), mt reversed.
__global__ __launch_bounds__(256, 3) void k_gemm_pv(const u16* __restrict__ P,
                                                    const u16* __restrict__ Vt,
                                                    const float* __restrict__ Srow,
                                                    float* __restrict__ O) {
    __shared__ u16 smem[16384];              // 32 KB
    const int nt = blockIdx.x, mt = 15 - blockIdx.y, b = blockIdx.z;
    const u16* Pp = P + (size_t)b * 2048 * 2048 + (size_t)mt * 128 * 2048;
    const u16* Vp = Vt + (size_t)b * 1024 * 2048 + (size_t)nt * 128 * 2048;
    f32x4 acc[4][4];
    gemm_core_nt(Pp, Vp, 2048, 2048, (mt + 1) * 128, smem, acc);
    float* Op = O + (size_t)b * 2048 * 1024;
    const float* Sr = Srow + (size_t)b * 2048;
    const int tid = threadIdx.x, wave = tid >> 6, lane = tid & 63;
    const int wm = (wave >> 1) * 64, wn = (wave & 1) * 64;
    const int row16 = lane & 15, quad = lane >> 4;
    float inv[4][4];
#pragma unroll
    for (int i = 0; i < 4; ++i)
#pragma unroll
        for (int r = 0; r < 4; ++r)
            inv[i][r] = 1.0f / Sr[mt * 128 + wm + i * 16 + quad * 4 + r];
#pragma unroll
    for (int i = 0; i < 4; ++i)
#pragma unroll
        for (int j = 0; j < 4; ++j) {
            int m = mt * 128 + wm + i * 16 + quad * 4;
            int n = nt * 128 + wn + j * 16 + row16;
#pragma unroll
            for (int r = 0; r < 4; ++r)
                Op[(size_t)(m + r) * 1024 + n] = acc[i][j][r] * inv[i][r];
        }
}

// ---------------- launcher ----------------
extern "C" void kernel_launch(void* const* d_in, const int* in_sizes, int n_in,
                              void* d_out, int out_size, void* d_ws, size_t ws_size,
                              hipStream_t stream) {
    const float* x  = (const float*)d_in[0];
    const float* Wq = (const float*)d_in[1];
    const float* Wk = (const float*)d_in[2];
    const float* Wv = (const float*)d_in[3];
    float* out = (float*)d_out;
    char* ws = (char*)d_ws;

    u16* xb  = (u16*)(ws);                          // 16 MB: x bf16 [8192,1024]
    u16* Wt3 = (u16*)(ws + (16u << 20));            //  6 MB: [Wq^T;Wk^T;Wv^T]
    u16* Qb  = (u16*)(ws + (22u << 20));            // 16 MB
    u16* Kb  = (u16*)(ws + (38u << 20));            // 16 MB
    u16* Vt  = (u16*)(ws + (54u << 20));            // 16 MB: V^T [B,1024,2048]
    u16* Sb  = (u16*)(ws + (70u << 20));            // 32 MB: P' [B,2048,2048]
    // Srow aliases xb (xb dead after proj; memset ordered after proj).
    float* Srow = (float*)ws;                       // 32 KB

    k_cvt_x<<<4096, 256, 0, stream>>>(x, xb, 8192 * 1024);
    k_cvt_w3<<<dim3(32, 32, 3), 256, 0, stream>>>(Wq, Wk, Wv, Wt3);

    k_gemm_proj<<<dim3(24, 64), 256, 0, stream>>>(xb, Wt3, Qb, Kb, Vt);

    hipMemsetAsync(Srow, 0, 8192 * sizeof(float), stream);
    k_gemm_scores<<<dim3(136, 4), 256, 0, stream>>>(Qb, Kb, Sb, Srow);
    k_gemm_pv<<<dim3(8, 16, 4), 256, 0, stream>>>(Sb, Vt, Srow, out);
}